// Round 10
// baseline (302.493 us; speedup 1.0000x reference)
//
#include <hip/hip_runtime.h>

// out[b,j,hw] = exp( sum_i log(relu(x[b,i,hw])+0.1) * E[i,j] ) + bias[j]
// x: (B=32, NC=64, H=128, W=128) fp32.
//
// R12: ADDRESS-DECORRELATION experiment. 8 structures (occ 17-70%, chunks
// 256B-2KB, reg/LDS staging, hand-vmcnt pipelines) ALL cap at 2.0-2.4 TB/s;
// fillBuffer streams 6.3 in the same session; per-CU in-flight bytes were
// 64-128KB (100x Little's-law need) -> service rate for the PATTERN is the
// cap. Untested variable: instantaneous address correlation. All prior
// kernels issue concurrent plane accesses at the SAME low-order offset, 64KB
// apart (addresses differ only in bits 16-21); channel/bank interleave keys
// on low bits -> all concurrent requests hit the same channel subset in
// lockstep (~2.4 TB/s ~ subset capacity). Explains: 256->512B helped (+20%),
// 512B->2KB flat (subset saturated), occupancy irrelevant.
// Fix under test: per-plane rotation ROT(p)=8*(p+(p>>3))&255 floats of each
// staged 1KB half-chunk (16B-granular, wraps in-half) -> concurrent accesses
// cover 32 distinct low-bit offsets. LDS reads apply the inverse rotation
// (pure index permutation: values bit-identical). ROT's 8*lg term replaces
// the old XOR swizzle: per-instruction banks = (C + ln - 8*lg) mod 32 ->
// exactly 2-way aliasing = free (m136). Stores: per-wave m-order stagger.
// Everything else IDENTICAL to R11 (88.3us, passed, absmax 0.015625).
// Success: hbm >=3500, dur 55-65us. Flat (85-90): pattern ceiling is
// fundamental -> ROOFLINE (200MB / 2.4 TB/s = 83us ~= measured).
#define NCH 64
#define HWSZ 16384
#define NPOINTS (32 * HWSZ)      // 524288
#define TPTS 512                 // points per tile
#define NBLK 512                 // 2 tiles per block
#define HPTS 256                 // points per half-tile (1KB chunks)

typedef __attribute__((ext_vector_type(8))) short bf16x8;  // 8 bf16, 4 VGPRs
typedef __attribute__((ext_vector_type(4))) float f32x4;

union fragU { bf16x8 v; unsigned int u[4]; };

static __device__ __forceinline__ unsigned int fbits(float f) {
    return __float_as_uint(f);
}
static __device__ __forceinline__ float bfup(unsigned int b) {
    return __uint_as_float(b & 0xFFFF0000u);
}

// per-plane rotation (in floats, multiple of 8, wraps within a 256-float half)
#define ROTF(P) (((((P) + ((P) >> 3))) << 3) & 255)

__global__ __launch_bounds__(512, 2) void fused_log_einsum_exp(
    const float* __restrict__ x,
    const float* __restrict__ E,     // (64,64) row-major: E[i*64+j]
    const float* __restrict__ bias,  // (64)
    float* __restrict__ out)
{
    __shared__ float lxs[NCH][TPTS];   // 64 x 512 x 4B = 128 KB

    const int lane = threadIdx.x & 63;
    const int wv   = threadIdx.x >> 6;   // wave 0..7
    const int lg   = lane >> 4;          // 0..3
    const int ln   = lane & 15;          // 0..15

    // ---- B-frags: E row-major (k=i, col=j), hi-only (entries bf16-exact).
    bf16x8 bE[4][2];
    #pragma unroll
    for (int m = 0; m < 4; ++m) {
        #pragma unroll
        for (int kk = 0; kk < 2; ++kk) {
            fragU h;
            #pragma unroll
            for (int w = 0; w < 4; ++w) {
                const int i0 = kk * 32 + lg * 8 + 2 * w;
                const int j  = m * 16 + ln;
                h.u[w] = (fbits(E[(i0 + 1) * NCH + j]) & 0xFFFF0000u)
                       | (fbits(E[i0 * NCH + j]) >> 16);
            }
            bE[m][kk] = h.v;
        }
    }
    float bj[4];
    #pragma unroll
    for (int m = 0; m < 4; ++m) bj[m] = bias[m * 16 + ln];

// float-index base of tile T (pt0 = T*512; 512 | HWSZ -> never crosses b)
#define TILE_PB(T) ((size_t)(((T) * TPTS) & ~(HWSZ - 1)) * NCH \
                  + (size_t)(((T) * TPTS) & (HWSZ - 1)))

// Stage half H of tile T: wave wv covers planes [wv*8, wv*8+8), one 1KB
// global_load_lds per plane. Source ROTATED within the half:
//   lds[p][H*256 + c] = x[p][H*256 + ((c + ROTF(p)) & 255)]
// (lane*4 and ROTF both multiples of 4 floats -> each lane's 16B run never
// crosses the 256 wrap). LDS dest linear (wave-uniform base + lane*16B).
#define STAGE(H, T) do {                                                       \
    const size_t pb_ = TILE_PB(T);                                             \
    _Pragma("unroll")                                                          \
    for (int n_ = 0; n_ < 8; ++n_) {                                           \
        const int p_ = wv * 8 + n_;                                            \
        const int f_ = (lane * 4 + ROTF(p_)) & 255;                            \
        const size_t g_ = pb_ + (size_t)p_ * HWSZ + (H) * HPTS + f_;           \
        __builtin_amdgcn_global_load_lds(                                      \
            (const __attribute__((address_space(1))) unsigned int*)(x + g_),   \
            (__attribute__((address_space(3))) unsigned int*)&lxs[p_][(H) * HPTS],\
            16, 0, 0);                                                         \
    }                                                                          \
} while (0)

// Compute half H of tile T. Read applies inverse rotation:
//   x[p][H*256+q] = lds[p][H*256 + ((q - ROTF(p)) & 255)]
// Banks per instr: (C + ln - 8*lg) mod 32 -> 2-way aliasing = free.
// A: lane holds A[row=pt=ln][k=lg*8+e], lx split hi/lo; B=E;
// D: lane,reg r -> [pt=lg*4+r][j=m*16+ln] => float4 stores.
// Store m-order staggered per wave (instantaneous plane-set decorrelation).
#define COMPUTE(H, T) do {                                                     \
    const size_t po_ = TILE_PB(T);                                             \
    _Pragma("unroll")                                                          \
    for (int sub_ = 0; sub_ < 2; ++sub_) {                                     \
        const int qb_ = wv * 32 + sub_ * 16 + ln;   /* within-half column */   \
        fragU ah_[2], al_[2];                                                  \
        _Pragma("unroll")                                                      \
        for (int kk_ = 0; kk_ < 2; ++kk_) {                                    \
            _Pragma("unroll")                                                  \
            for (int w_ = 0; w_ < 4; ++w_) {                                   \
                const int i0_ = kk_ * 32 + lg * 8 + 2 * w_;                    \
                const float v0_ = lxs[i0_]                                     \
                    [(H) * HPTS + ((qb_ - ROTF(i0_)) & 255)];                  \
                const float v1_ = lxs[i0_ + 1]                                 \
                    [(H) * HPTS + ((qb_ - ROTF(i0_ + 1)) & 255)];              \
                const float a0_ = __logf(fmaxf(v0_, 0.0f) + 0.1f);             \
                const float a1_ = __logf(fmaxf(v1_, 0.0f) + 0.1f);             \
                ah_[kk_].u[w_] = (fbits(a1_) & 0xFFFF0000u) | (fbits(a0_) >> 16); \
                const float b0_ = a0_ - bfup(fbits(a0_));                      \
                const float b1_ = a1_ - bfup(fbits(a1_));                      \
                al_[kk_].u[w_] = (fbits(b1_) & 0xFFFF0000u) | (fbits(b0_) >> 16); \
            }                                                                  \
        }                                                                      \
        _Pragma("unroll")                                                      \
        for (int mi_ = 0; mi_ < 4; ++mi_) {                                    \
            const int m_ = (mi_ + wv) & 3;                                     \
            f32x4 acc_ = {0.f, 0.f, 0.f, 0.f};                                 \
            _Pragma("unroll")                                                  \
            for (int kk_ = 0; kk_ < 2; ++kk_) {                                \
                acc_ = __builtin_amdgcn_mfma_f32_16x16x32_bf16(                \
                           ah_[kk_].v, bE[m_][kk_], acc_, 0, 0, 0);            \
                acc_ = __builtin_amdgcn_mfma_f32_16x16x32_bf16(                \
                           al_[kk_].v, bE[m_][kk_], acc_, 0, 0, 0);            \
            }                                                                  \
            float4 o_;                                                         \
            o_.x = __expf(acc_[0]) + bj[m_];                                   \
            o_.y = __expf(acc_[1]) + bj[m_];                                   \
            o_.z = __expf(acc_[2]) + bj[m_];                                   \
            o_.w = __expf(acc_[3]) + bj[m_];                                   \
            *reinterpret_cast<float4*>(out + po_                               \
                + (size_t)(m_ * 16 + ln) * HWSZ                                \
                + (size_t)((H) * HPTS + wv * 32 + sub_ * 16 + lg * 4)) = o_;   \
        }                                                                      \
    }                                                                          \
} while (0)

#define WAIT8_BARRIER do {                                                     \
    asm volatile("s_waitcnt vmcnt(8)" ::: "memory");                           \
    __builtin_amdgcn_s_barrier();                                              \
    __builtin_amdgcn_sched_barrier(0);                                         \
} while (0)

    const int t0 = (int)blockIdx.x;        // tile 0
    const int t1 = t0 + NBLK;              // tile 1

    // Per-wave vmem issue order (batches of 8, in-order retirement):
    //   H0(t0) H1(t0) | st(H0,t0) H0(t1) | st(H1,t0) H1(t1) | st(H0,t1) ...
    // => every "half ready" wait is exactly vmcnt(8). Never 0.
    STAGE(0, t0);
    STAGE(1, t0);
    WAIT8_BARRIER;            // H0(t0) landed; H1(t0) in flight
    COMPUTE(0, t0);
    WAIT8_BARRIER;            // H1(t0) landed; readers of H0(t0) done
    STAGE(0, t1);             // restage H0 under COMPUTE(H1)
    COMPUTE(1, t0);
    WAIT8_BARRIER;            // H0(t1) landed; readers of H1(t0) done
    STAGE(1, t1);             // restage H1 under COMPUTE(H0)
    COMPUTE(0, t1);
    WAIT8_BARRIER;            // H1(t1) landed
    COMPUTE(1, t1);           // final stores drain at kernel end

#undef TILE_PB
#undef STAGE
#undef COMPUTE
#undef WAIT8_BARRIER
}

extern "C" void kernel_launch(void* const* d_in, const int* in_sizes, int n_in,
                              void* d_out, int out_size, void* d_ws, size_t ws_size,
                              hipStream_t stream) {
    const float* x    = (const float*)d_in[0];
    const float* E    = (const float*)d_in[1];   // (64,64,1,1) -> [i*64+j]
    const float* bias = (const float*)d_in[2];   // (64,1,1)
    float* out = (float*)d_out;

    dim3 grid(NBLK), block(512);
    hipLaunchKernelGGL(fused_log_einsum_exp, grid, block, 0, stream,
                       x, E, bias, out);
}